// Round 3
// 214.807 us; speedup vs baseline: 1.0208x; 1.0208x over previous
//
#include <hip/hip_runtime.h>
#include <math.h>

#define H 2048
#define E 64
#define MR 16        // rows per block (was 32; halves LDS -> ~7 blocks/CU)
#define KCH 128      // k per chunk
#define NCH 16       // chunks
#define LR 136       // LDS row stride in f16 (128 + 8 pad; 272 B rows, 16B-aligned)

typedef _Float16 half8  __attribute__((ext_vector_type(8)));
typedef _Float16 half4h __attribute__((ext_vector_type(4)));
typedef float    f32x4  __attribute__((ext_vector_type(4)));

#define MFMA16(A,B,C) __builtin_amdgcn_mfma_f32_16x16x32_f16(A,B,C,0,0,0)

// ws layout: Bh[H*E f16] | Bl[H*E f16] | csum[E f32] | bsum[E f32]

// Pack W' = lnw*W into MFMA B-fragment layout, f16 hi/lo split (lo scaled by 2048).
// Fragment (ks, et): lane l holds B[k = ks*32 + (l>>4)*8 + j][n = et*16 + (l&15)], j=0..7.
__global__ __launch_bounds__(256) void prep_pack(const float* __restrict__ W,
        const float* __restrict__ lnw, _Float16* __restrict__ Bh,
        _Float16* __restrict__ Bl) {
    int idx  = blockIdx.x * 256 + threadIdx.x;      // 0..16383
    int lane = idx & 63;
    int ks   = idx >> 8;                            // 0..63
    int e  = ((idx >> 6) & 3) * 16 + (lane & 15);
    int k0 = ks * 32 + ((lane >> 4) << 3);
    half8 hh, ll;
    #pragma unroll
    for (int j = 0; j < 8; ++j) {
        float wf = lnw[k0 + j] * W[e * H + k0 + j];
        _Float16 h = (_Float16)wf;
        _Float16 l = (_Float16)((wf - (float)h) * 2048.0f);
        hh[j] = h; ll[j] = l;
    }
    *(half8*)&Bh[(long)idx * 8] = hh;
    *(half8*)&Bl[(long)idx * 8] = ll;
}

__global__ __launch_bounds__(256) void prep_sums(const float* __restrict__ W,
        const float* __restrict__ lnw, const float* __restrict__ lnb,
        float* __restrict__ csum, float* __restrict__ bsum) {
    __shared__ float rc[256], rb[256];
    int e = blockIdx.x, t = threadIdx.x;
    float cs = 0.f, bs = 0.f;
    #pragma unroll
    for (int j = 0; j < 8; ++j) {
        int k = t + j * 256;
        float w = W[e * H + k];
        cs += lnw[k] * w;
        bs += lnb[k] * w;
    }
    rc[t] = cs; rb[t] = bs;
    __syncthreads();
    for (int s = 128; s > 0; s >>= 1) {
        if (t < s) { rc[t] += rc[t + s]; rb[t] += rb[t + s]; }
        __syncthreads();
    }
    if (t == 0) { csum[e] = rc[0]; bsum[e] = rb[0]; }
}

__global__ __launch_bounds__(256, 6) void router_kernel(
    const float* __restrict__ X, const _Float16* __restrict__ Bh,
    const _Float16* __restrict__ Bl, const float* __restrict__ csum,
    const float* __restrict__ bsum, float* __restrict__ out, int nRows)
{
    __shared__ __align__(16) _Float16 Xh[2][MR][LR];   // 8,704 B
    __shared__ __align__(16) _Float16 Xl[2][MR][LR];   // 8,704 B
    __shared__ float C2[MR][E + 4];                    // 4,352 B
    __shared__ float mu_s[MR], rs_s[MR];
    // ~21.9 KB total -> 7 blocks/CU LDS capacity (was 44 KB / 2-3 blocks)

    const int t    = threadIdx.x;
    const int lane = t & 63;
    const int et   = t >> 6;                 // wave -> expert tile (16 experts)
    const int q    = lane >> 4;
    const int ln16 = lane & 15;
    const int rowR = t >> 4;                 // staging/stats row 0..15 (16 thr/row)
    const int cS   = t & 15;                 // float4 col group within chunk
    const long rowBase = (long)blockIdx.x * MR;
    const long iOff = (long)nRows * 2;
    const long lOff = (long)nRows * 4;

    const float4* X4 = (const float4*)X;
    const float4* Xrow = X4 + (rowBase + rowR) * 512;

    float sacc = 0.f, qacc = 0.f;            // LN stats, fixed row per thread

    // convert helper writes vb -> buf (2 float4 per thread per chunk)
    auto convert = [&](const float4* vb, int buf) {
        #pragma unroll
        for (int j = 0; j < 2; ++j) {
            float4 v = vb[j];
            sacc += v.x + v.y + v.z + v.w;
            qacc += v.x * v.x + v.y * v.y + v.z * v.z + v.w * v.w;
            _Float16 h0 = (_Float16)v.x, h1 = (_Float16)v.y,
                     h2 = (_Float16)v.z, h3 = (_Float16)v.w;
            _Float16 l0 = (_Float16)((v.x - (float)h0) * 2048.f);
            _Float16 l1 = (_Float16)((v.y - (float)h1) * 2048.f);
            _Float16 l2 = (_Float16)((v.z - (float)h2) * 2048.f);
            _Float16 l3 = (_Float16)((v.w - (float)h3) * 2048.f);
            half4h hh = {h0, h1, h2, h3};
            half4h ll = {l0, l1, l2, l3};
            int col = (cS + j * 16) * 4;
            *(half4h*)&Xh[buf][rowR][col] = hh;
            *(half4h*)&Xl[buf][rowR][col] = ll;
        }
    };

    // prologue: chunk 0 load + convert
    {
        float4 vb[2];
        #pragma unroll
        for (int j = 0; j < 2; ++j) vb[j] = Xrow[cS + j * 16];
        convert(vb, 0);
    }
    __syncthreads();

    f32x4 acc0 = (f32x4)0.f;
    f32x4 acc1 = (f32x4)0.f;

    for (int c = 0; c < NCH; ++c) {
        const int buf = c & 1;

        // ---- W burst for chunk c (oldest in vmcnt FIFO) ----
        half8 Wh[4], Wl[4];
        #pragma unroll
        for (int ks = 0; ks < 4; ++ks) {
            int bo = (((c * 4 + ks) * 4 + et) * 64 + lane) * 8;
            Wh[ks] = *(const half8*)&Bh[bo];
            Wl[ks] = *(const half8*)&Bl[bo];
        }
        // ---- X burst for chunk c+1 (newer -> W-uses don't wait on it) ----
        float4 vb[2];
        if (c + 1 < NCH) {
            #pragma unroll
            for (int j = 0; j < 2; ++j)
                vb[j] = Xrow[(c + 1) * 32 + cS + j * 16];
        }

        // ---- MFMA over chunk c (single 16-row m-tile) ----
        #pragma unroll
        for (int ks = 0; ks < 4; ++ks) {
            half8 Ah = *(const half8*)&Xh[buf][ln16][ks * 32 + q * 8];
            half8 Al = *(const half8*)&Xl[buf][ln16][ks * 32 + q * 8];
            acc0 = MFMA16(Ah, Wh[ks], acc0);
            acc1 = MFMA16(Ah, Wl[ks], acc1);
            acc1 = MFMA16(Al, Wh[ks], acc1);
        }

        // ---- convert chunk c+1 into other buffer (WAR-safe: barrier below) ----
        if (c + 1 < NCH) convert(vb, buf ^ 1);
        __syncthreads();
    }

    // ---- finalize LN stats (16 lanes per row: bits 0-3 of lane) ----
    {
        float s = sacc, qq = qacc;
        #pragma unroll
        for (int d = 1; d < 16; d <<= 1) {
            s  += __shfl_xor(s, d);
            qq += __shfl_xor(qq, d);
        }
        if (cS == 0) {
            float mu  = s * (1.f / H);
            float var = qq * (1.f / H) - mu * mu;
            mu_s[rowR] = mu;
            rs_s[rowR] = rsqrtf(var + 1e-5f);
        }
    }
    __syncthreads();

    // ---- epilogue: combine splits, LN rank-1 correction, clip, write logits ----
    {
        int n = et * 16 + ln16;
        float cs = csum[n], bs = bsum[n];
        #pragma unroll
        for (int reg = 0; reg < 4; ++reg) {
            int r = q * 4 + reg;
            float raw = acc0[reg] + acc1[reg] * (1.f / 2048.f);
            float lg = rs_s[r] * (raw - mu_s[r] * cs) + bs;
            lg = fminf(fmaxf(lg, -10.f), 10.f);
            out[lOff + (rowBase + r) * 64 + n] = lg;
            C2[r][n] = lg;
        }
    }
    __syncthreads();

    // ---- softmax + top2: wave et handles rows et*4 .. et*4+3 ----
    #pragma unroll
    for (int rr = 0; rr < 4; ++rr) {
        int r = et * 4 + rr;
        float l = C2[r][lane];
        float m = l;
        #pragma unroll
        for (int d = 1; d < 64; d <<= 1) m = fmaxf(m, __shfl_xor(m, d));
        float p = __expf(l - m);
        float ssum = p;
        #pragma unroll
        for (int d = 1; d < 64; d <<= 1) ssum += __shfl_xor(ssum, d);
        float prob = fminf(fmaxf(p / ssum, 1e-4f), 1.0f);

        float v1 = prob; int i1 = lane;
        #pragma unroll
        for (int d = 1; d < 64; d <<= 1) {
            float ov = __shfl_xor(v1, d);
            int   oi = __shfl_xor(i1, d);
            if (ov > v1 || (ov == v1 && oi < i1)) { v1 = ov; i1 = oi; }
        }
        float v2 = (lane == i1) ? -1.f : prob; int i2 = lane;
        #pragma unroll
        for (int d = 1; d < 64; d <<= 1) {
            float ov = __shfl_xor(v2, d);
            int   oi = __shfl_xor(i2, d);
            if (ov > v2 || (ov == v2 && oi < i2)) { v2 = ov; i2 = oi; }
        }
        if (lane == 0) {
            float ps = fmaxf(v1 + v2, 1e-4f);
            long rg_ = rowBase + r;
            out[rg_ * 2 + 0] = v1 / ps;
            out[rg_ * 2 + 1] = v2 / ps;
            out[iOff + rg_ * 2 + 0] = (float)i1;
            out[iOff + rg_ * 2 + 1] = (float)i2;
        }
    }
}

extern "C" void kernel_launch(void* const* d_in, const int* in_sizes, int n_in,
                              void* d_out, int out_size, void* d_ws, size_t ws_size,
                              hipStream_t stream) {
    const float* X   = (const float*)d_in[0];
    const float* lnw = (const float*)d_in[1];
    const float* lnb = (const float*)d_in[2];
    const float* W   = (const float*)d_in[3];
    float* outp = (float*)d_out;

    _Float16* Bh = (_Float16*)d_ws;
    _Float16* Bl = Bh + H * E;
    float* csum  = (float*)(Bl + H * E);
    float* bsum  = csum + E;

    int N = in_sizes[0] / H;                 // 16384 rows

    prep_pack<<<(H * E / 8) / 256, 256, 0, stream>>>(W, lnw, Bh, Bl);
    prep_sums<<<E, 256, 0, stream>>>(W, lnw, lnb, csum, bsum);
    router_kernel<<<N / MR, 256, 0, stream>>>(X, Bh, Bl, csum, bsum, outp, N);
}